// Round 1
// baseline (655.783 us; speedup 1.0000x reference)
//
#include <hip/hip_runtime.h>
#include <hip/hip_bf16.h>

#define NNODES 32
#define TSTEPS 49
#define NEDGE  992
#define ROWS_E 7936     // B*E
#define ROWS_OUT 12544  // B*T*N
#define EPSV 1e-5f

typedef __hip_bfloat16 bf16;
typedef __attribute__((ext_vector_type(8))) short bf16x8;
typedef __attribute__((ext_vector_type(4))) float f32x4;

__device__ inline float eluf(float x){ return x > 0.f ? x : (__expf(x) - 1.f); }
__device__ inline float bfu2f(unsigned short u){ unsigned v = ((unsigned)u) << 16; return *reinterpret_cast<float*>(&v); }
__device__ inline unsigned pack_bf16(float a, float b){
  __hip_bfloat16 ha = __float2bfloat16(a), hb = __float2bfloat16(b);
  unsigned short ua = *reinterpret_cast<unsigned short*>(&ha);
  unsigned short ub = *reinterpret_cast<unsigned short*>(&hb);
  return (unsigned)ua | ((unsigned)ub << 16);
}

// ---------------- weight prep: transpose + bf16 convert ----------------
__global__ void prep_weights(const float* e2w1, const float* e2w2, const float* e4w1, const float* e4w2,
                             const float* mw2, const float* ow1, const float* ow2,
                             bf16* w2aT, bf16* w2bT, bf16* w4aT, bf16* w4bT,
                             bf16* mw2T, bf16* ow1T, bf16* ow2T){
  int i = blockIdx.x*256 + threadIdx.x;
  if (i < 131072){ int n = i >> 9, c = i & 511; w2aT[i] = __float2bfloat16(e2w1[c*256+n]); return; } i -= 131072;
  if (i < 65536) { int n = i >> 8, c = i & 255; w2bT[i] = __float2bfloat16(e2w2[c*256+n]); return; } i -= 65536;
  if (i < 196608){ int n = i / 768, c = i % 768; w4aT[i] = __float2bfloat16(e4w1[c*256+n]); return; } i -= 196608;
  if (i < 65536) { int n = i >> 8, c = i & 255; w4bT[i] = __float2bfloat16(e4w2[c*256+n]); return; } i -= 65536;
  if (i < 262144){ int k = i >> 16, r = i & 65535; int n = r >> 8, c = r & 255;
                   mw2T[i] = __float2bfloat16(mw2[(k*256+c)*256+n]); return; } i -= 262144;
  if (i < 73728) { int n = i / 288, c = i % 288;
                   ow1T[i] = (c < 260) ? __float2bfloat16(ow1[c*256+n]) : __float2bfloat16(0.f); return; } i -= 73728;
  if (i < 65536) { int n = i >> 8, c = i & 255; ow2T[i] = __float2bfloat16(ow2[c*256+n]); return; }
}

// ---------------- small 2-layer ELU MLP (256 rows), fp32 VALU ----------------
template<int KIN>
__global__ void small_mlp(const float* __restrict__ X, const float* __restrict__ w1, const float* __restrict__ b1,
                          const float* __restrict__ w2, const float* __restrict__ b2, float* __restrict__ H){
  __shared__ float xs[KIN];
  __shared__ float h1[256];
  int r = blockIdx.x, f = threadIdx.x;
  for (int c = f; c < KIN; c += 256) xs[c] = X[(size_t)r*KIN + c];
  __syncthreads();
  float acc = b1[f];
  for (int c = 0; c < KIN; c++) acc = fmaf(xs[c], w1[c*256+f], acc);
  h1[f] = eluf(acc);
  __syncthreads();
  float a2 = b2[f];
  for (int c = 0; c < 256; c++) a2 = fmaf(h1[c], w2[c*256+f], a2);
  H[(size_t)r*256 + f] = eluf(a2);
}

// BN over 256 rows (single block); writes bf16 normalized
__global__ void bn_small(const float* __restrict__ H, const float* __restrict__ g, const float* __restrict__ be,
                         bf16* __restrict__ Xout){
  int f = threadIdx.x;
  float s = 0.f, s2 = 0.f;
  for (int r = 0; r < 256; r++){ float v = H[r*256+f]; s += v; s2 += v*v; }
  float m = s * (1.f/256.f), var = s2 * (1.f/256.f) - m*m;
  float sc = g[f] * rsqrtf(var + EPSV), sh = be[f] - m*sc;
  for (int r = 0; r < 256; r++) Xout[r*256+f] = __float2bfloat16(H[r*256+f]*sc + sh);
}

// ---------------- gathers ----------------
__global__ void gather2(const bf16* __restrict__ X, const int* __restrict__ send, const int* __restrict__ recv,
                        bf16* __restrict__ A){
  int i = blockIdx.x*256 + threadIdx.x;           // one uint4 (8 bf16) each; 7936*64 total
  int row = i >> 6, ch = i & 63;
  int b = row / NEDGE, e = row % NEDGE;
  int c8 = ch*8;
  int src_n = (c8 < 256) ? send[e] : recv[e];
  int c = c8 & 255;
  *reinterpret_cast<uint4*>(A + (size_t)row*512 + c8) =
      *reinterpret_cast<const uint4*>(X + (size_t)(b*NNODES + src_n)*256 + c);
}

__global__ void gather3(const bf16* __restrict__ X3, const bf16* __restrict__ X2,
                        const int* __restrict__ send, const int* __restrict__ recv, bf16* __restrict__ A){
  int i = blockIdx.x*256 + threadIdx.x;           // 7936*96 total
  int row = i / 96, ch = i % 96;
  int b = row / NEDGE, e = row % NEDGE;
  int c8 = ch*8;
  const bf16* src;
  if (c8 < 256)       src = X3 + (size_t)(b*NNODES + send[e])*256 + c8;
  else if (c8 < 512)  src = X3 + (size_t)(b*NNODES + recv[e])*256 + (c8-256);
  else                src = X2 + (size_t)row*256 + (c8-512);
  *reinterpret_cast<uint4*>(A + (size_t)row*768 + c8) = *reinterpret_cast<const uint4*>(src);
}

// ---------------- generic MFMA GEMM: Y = act(A @ W + b), N=256, M%128==0 ----------------
// A: bf16 MxK row-major; WT: bf16 256xK row-major (i.e. W transposed)
template<int K, int ACT, bool OBF>
__global__ __launch_bounds__(256,2) void gemm_mfma(const bf16* __restrict__ A, const bf16* __restrict__ WT,
                                                   const float* __restrict__ bias, void* __restrict__ Y){
  int mb = blockIdx.x;
  int tid = threadIdx.x;
  int w = tid >> 6, l = tid & 63, l15 = l & 15, lq = l >> 4;
  f32x4 acc[8][4];
  #pragma unroll
  for (int m = 0; m < 8; m++)
    #pragma unroll
    for (int nt = 0; nt < 4; nt++) acc[m][nt] = (f32x4){0.f,0.f,0.f,0.f};
  const bf16* Ab = A + (size_t)mb*128*K;
  int nw = w*64;
  for (int s = 0; s < K/32; s++){
    int c0 = s*32 + lq*8;
    bf16x8 bfr[4];
    #pragma unroll
    for (int nt = 0; nt < 4; nt++){
      int fcol = nw + nt*16 + l15;
      bfr[nt] = *reinterpret_cast<const bf16x8*>(WT + (size_t)fcol*K + c0);
    }
    #pragma unroll
    for (int m = 0; m < 8; m++){
      bf16x8 afr = *reinterpret_cast<const bf16x8*>(Ab + (size_t)(m*16 + l15)*K + c0);
      #pragma unroll
      for (int nt = 0; nt < 4; nt++)
        acc[m][nt] = __builtin_amdgcn_mfma_f32_16x16x32_bf16(afr, bfr[nt], acc[m][nt], 0, 0, 0);
    }
  }
  #pragma unroll
  for (int m = 0; m < 8; m++)
    #pragma unroll
    for (int nt = 0; nt < 4; nt++){
      int fcol = nw + nt*16 + l15;
      float bv = bias[fcol];
      #pragma unroll
      for (int v = 0; v < 4; v++){
        int row = mb*128 + m*16 + lq*4 + v;
        float val = acc[m][nt][v] + bv;
        if (ACT == 1) val = fmaxf(val, 0.f);
        else if (ACT == 2) val = eluf(val);
        if (OBF) ((bf16*)Y)[(size_t)row*256 + fcol] = __float2bfloat16(val);
        else     ((float*)Y)[(size_t)row*256 + fcol] = val;
      }
    }
}

// ---------------- batchnorm over 7936 rows ----------------
__global__ void bn_stats(const float* __restrict__ Y, float* __restrict__ part){
  int f = threadIdx.x;
  int r0 = blockIdx.x*64;
  float s = 0.f, s2 = 0.f;
  for (int r = 0; r < 64; r++){ float v = Y[(size_t)(r0+r)*256 + f]; s += v; s2 += v*v; }
  part[blockIdx.x*512 + f] = s;
  part[blockIdx.x*512 + 256 + f] = s2;
}
__global__ void bn_finalize(const float* __restrict__ part, int nb, const float* __restrict__ g,
                            const float* __restrict__ be, float* __restrict__ prm, float nrows){
  int f = threadIdx.x;
  float s = 0.f, s2 = 0.f;
  for (int i = 0; i < nb; i++){ s += part[i*512+f]; s2 += part[i*512+256+f]; }
  float m = s / nrows, var = s2 / nrows - m*m;
  float sc = g[f] * rsqrtf(var + EPSV);
  prm[f] = sc; prm[256+f] = be[f] - m*sc;
}
__global__ void bn_apply(const float* __restrict__ Y, const float* __restrict__ prm, bf16* __restrict__ X){
  int i = blockIdx.x*256 + threadIdx.x;
  int f = i & 255;
  X[i] = __float2bfloat16(Y[i]*prm[f] + prm[256+f]);
}

// ---------------- incoming = segment-sum over 31 edges / N ----------------
__global__ void seg_incoming(const bf16* __restrict__ X2, float* __restrict__ inc){
  int bn = blockIdx.x; int b = bn >> 5, n = bn & 31;
  int f = threadIdx.x;
  const bf16* p = X2 + (size_t)(b*NEDGE + n*31)*256 + f;
  float s = 0.f;
  for (int j = 0; j < 31; j++) s += __bfloat162float(p[j*256]);
  inc[bn*256 + f] = s * (1.f/32.f);
}

// ---------------- fc + softmax (prob out, rel_type to ws) ----------------
__global__ void fc_softmax(const bf16* __restrict__ X4, const float* __restrict__ fcw, const float* __restrict__ fcb,
                           const float* __restrict__ gumbel, float* __restrict__ prob_out, float* __restrict__ rt){
  int r = blockIdx.x*256 + threadIdx.x;
  if (r >= ROWS_E) return;
  float l0 = fcb[0], l1 = fcb[1], l2 = fcb[2], l3 = fcb[3];
  const bf16* xr = X4 + (size_t)r*256;
  for (int c = 0; c < 256; c += 8){
    uint4 u = *reinterpret_cast<const uint4*>(xr + c);
    unsigned uu[4] = {u.x, u.y, u.z, u.w};
    #pragma unroll
    for (int q = 0; q < 4; q++){
      float x0 = bfu2f((unsigned short)(uu[q] & 0xffff));
      float x1 = bfu2f((unsigned short)(uu[q] >> 16));
      int cc = c + 2*q;
      float4 w0 = *reinterpret_cast<const float4*>(fcw + cc*4);
      float4 w1 = *reinterpret_cast<const float4*>(fcw + (cc+1)*4);
      l0 += x0*w0.x + x1*w1.x; l1 += x0*w0.y + x1*w1.y;
      l2 += x0*w0.z + x1*w1.z; l3 += x0*w0.w + x1*w1.w;
    }
  }
  // prob = softmax(logits)
  float mx = fmaxf(fmaxf(l0,l1), fmaxf(l2,l3));
  float e0 = __expf(l0-mx), e1 = __expf(l1-mx), e2 = __expf(l2-mx), e3 = __expf(l3-mx);
  float inv = 1.f / (e0+e1+e2+e3);
  prob_out[(size_t)r*4+0] = e0*inv; prob_out[(size_t)r*4+1] = e1*inv;
  prob_out[(size_t)r*4+2] = e2*inv; prob_out[(size_t)r*4+3] = e3*inv;
  // rel_type = softmax((logits+gumbel)/0.5)
  float4 gv = *reinterpret_cast<const float4*>(gumbel + (size_t)r*4);
  float t0 = (l0+gv.x)*2.f, t1 = (l1+gv.y)*2.f, t2 = (l2+gv.z)*2.f, t3 = (l3+gv.w)*2.f;
  float mx2 = fmaxf(fmaxf(t0,t1), fmaxf(t2,t3));
  float f0 = __expf(t0-mx2), f1 = __expf(t1-mx2), f2 = __expf(t2-mx2), f3 = __expf(t3-mx2);
  float inv2 = 1.f / (f0+f1+f2+f3);
  rt[(size_t)r*4+0] = f0*inv2; rt[(size_t)r*4+1] = f1*inv2;
  rt[(size_t)r*4+2] = f2*inv2; rt[(size_t)r*4+3] = f3*inv2;
}

// ---------------- fused decoder message passing ----------------
// block: one (b,t) x 4 receivers (128 padded rows). 3 edge-types fused, in-block
// segment reduction (edges of receiver n are exactly [31n,31n+31)), writes aug rows.
__global__ __launch_bounds__(256,2) void decoder_msg(
    const float* __restrict__ data, const int* __restrict__ send,
    const float* __restrict__ rt, const float* __restrict__ mw1,
    const float* __restrict__ mb1, const bf16* __restrict__ mw2T,
    const float* __restrict__ mb2, bf16* __restrict__ Aaug){
  __shared__ __align__(16) float pm[128][8];
  __shared__ __align__(16) float rts[128][4];
  __shared__ __align__(16) float aggl[4][256];
  __shared__ __align__(16) short hA[128*256];   // 64KB, xor-swizzled bf16
  int bx = blockIdx.x;
  int bt = bx >> 3, rg = bx & 7;
  int b = bt / TSTEPS, t = bt % TSTEPS;
  int n0 = rg * 4;
  int tid = threadIdx.x;
  {
    int r = tid >> 1, half = tid & 1;
    int g = r >> 5, j = r & 31;
    int n = n0 + g;
    float4 v = make_float4(0.f,0.f,0.f,0.f);
    if (j < 31){
      int e = n*31 + j;
      int src = half ? n : send[e];
      v = *reinterpret_cast<const float4*>(data + ((size_t)(b*NNODES + src)*TSTEPS + t)*4);
    }
    *reinterpret_cast<float4*>(&pm[r][half*4]) = v;
    if (half == 0){
      float4 rv = make_float4(0.f,0.f,0.f,0.f);
      if (j < 31){
        int e = n*31 + j;
        rv = *reinterpret_cast<const float4*>(rt + ((size_t)b*NEDGE + e)*4);
      }
      *reinterpret_cast<float4*>(&rts[r][0]) = rv;
    }
  }
  for (int i = tid; i < 1024; i += 256) ((float*)aggl)[i] = 0.f;
  __syncthreads();

  int w = tid >> 6, l = tid & 63, l15 = l & 15, lq = l >> 4;

  for (int kk = 1; kk < 4; kk++){
    { // h1 = relu(pm @ mw1[kk] + mb1[kk]) -> hA
      int p = tid & 127, hf = tid >> 7;
      float wv0[8], wv1[8];
      #pragma unroll
      for (int c = 0; c < 8; c++){
        float2 ww = *reinterpret_cast<const float2*>(mw1 + ((size_t)kk*8 + c)*256 + 2*p);
        wv0[c] = ww.x; wv1[c] = ww.y;
      }
      float2 bbv = *reinterpret_cast<const float2*>(mb1 + kk*256 + 2*p);
      for (int r = hf*64; r < hf*64 + 64; r++){
        float a0 = bbv.x, a1 = bbv.y;
        #pragma unroll
        for (int c = 0; c < 8; c++){ float x = pm[r][c]; a0 = fmaf(x, wv0[c], a0); a1 = fmaf(x, wv1[c], a1); }
        a0 = fmaxf(a0, 0.f); a1 = fmaxf(a1, 0.f);
        int byteoff = r*512 + ((4*p) ^ ((r & 7) << 4));
        *reinterpret_cast<unsigned*>(reinterpret_cast<char*>(hA) + byteoff) = pack_bf16(a0, a1);
      }
    }
    __syncthreads();

    f32x4 acc[8][4];
    #pragma unroll
    for (int m = 0; m < 8; m++)
      #pragma unroll
      for (int nt = 0; nt < 4; nt++) acc[m][nt] = (f32x4){0.f,0.f,0.f,0.f};
    const bf16* wk = mw2T + (size_t)kk*65536;
    for (int s = 0; s < 8; s++){
      int c0 = s*32 + lq*8;
      bf16x8 bfr[4];
      #pragma unroll
      for (int nt = 0; nt < 4; nt++){
        int fcol = w*64 + nt*16 + l15;
        bfr[nt] = *reinterpret_cast<const bf16x8*>(wk + (size_t)fcol*256 + c0);
      }
      #pragma unroll
      for (int m = 0; m < 8; m++){
        int row = m*16 + l15;
        int byteoff = row*512 + ((s*64 + lq*16) ^ ((row & 7) << 4));
        bf16x8 af = *reinterpret_cast<const bf16x8*>(reinterpret_cast<const char*>(hA) + byteoff);
        #pragma unroll
        for (int nt = 0; nt < 4; nt++)
          acc[m][nt] = __builtin_amdgcn_mfma_f32_16x16x32_bf16(af, bfr[nt], acc[m][nt], 0, 0, 0);
      }
    }
    // epilogue: relu(+b2), weight by rel_type, reduce rows into per-receiver agg
    #pragma unroll
    for (int m = 0; m < 8; m++){
      int g = m >> 1;
      #pragma unroll
      for (int nt = 0; nt < 4; nt++){
        int fcol = w*64 + nt*16 + l15;
        float bv = mb2[kk*256 + fcol];
        float ssum = 0.f;
        #pragma unroll
        for (int v = 0; v < 4; v++){
          int row = m*16 + lq*4 + v;
          float msg = fmaxf(acc[m][nt][v] + bv, 0.f);
          ssum += msg * rts[row][kk];
        }
        ssum += __shfl_xor(ssum, 16);
        ssum += __shfl_xor(ssum, 32);
        if (lq == 0) aggl[g][fcol] += ssum;
      }
    }
    __syncthreads();
  }

  // write aug rows: [data(4) | agg(256) | pad(28)] as bf16, K=288
  for (int i = tid; i < 4*288; i += 256){
    int g = i / 288, c = i % 288;
    float val;
    if (c < 4)        val = pm[g*32][4 + c];
    else if (c < 260) val = aggl[g][c - 4];
    else              val = 0.f;
    Aaug[(size_t)(bt*NNODES + n0 + g)*288 + c] = __float2bfloat16(val);
  }
}

// ---------------- final: p3 = P2 @ ow3 + ob3 ; out = data + p3 (t<48) ----------------
__global__ void final_out(const bf16* __restrict__ P2, const float* __restrict__ ow3,
                          const float* __restrict__ ob3, const float* __restrict__ data,
                          float* __restrict__ out){
  int r = blockIdx.x*256 + threadIdx.x;
  if (r >= ROWS_OUT) return;
  int bt = r >> 5, n = r & 31;
  int b = bt / TSTEPS, t = bt % TSTEPS;
  float a0 = ob3[0], a1 = ob3[1], a2 = ob3[2], a3 = ob3[3];
  const bf16* pr = P2 + (size_t)r*256;
  for (int c = 0; c < 256; c += 8){
    uint4 u = *reinterpret_cast<const uint4*>(pr + c);
    unsigned uu[4] = {u.x, u.y, u.z, u.w};
    #pragma unroll
    for (int q = 0; q < 4; q++){
      float x0 = bfu2f((unsigned short)(uu[q] & 0xffff));
      float x1 = bfu2f((unsigned short)(uu[q] >> 16));
      int cc = c + 2*q;
      float4 w0 = *reinterpret_cast<const float4*>(ow3 + cc*4);
      float4 w1 = *reinterpret_cast<const float4*>(ow3 + (cc+1)*4);
      a0 += x0*w0.x + x1*w1.x; a1 += x0*w0.y + x1*w1.y;
      a2 += x0*w0.z + x1*w1.z; a3 += x0*w0.w + x1*w1.w;
    }
  }
  if (t < TSTEPS-1){
    float4 dv = *reinterpret_cast<const float4*>(data + ((size_t)(b*NNODES + n)*TSTEPS + t)*4);
    float4 o; o.x = dv.x + a0; o.y = dv.y + a1; o.z = dv.z + a2; o.w = dv.w + a3;
    *reinterpret_cast<float4*>(out + ((size_t)(b*NNODES + n)*(TSTEPS-1) + t)*4) = o;
  }
}

// ---------------- launcher ----------------
extern "C" void kernel_launch(void* const* d_in, const int* in_sizes, int n_in,
                              void* d_out, int out_size, void* d_ws, size_t ws_size,
                              hipStream_t stream){
  const float* data    = (const float*)d_in[0];
  const float* gumbel  = (const float*)d_in[1];
  const int*   recv_idx= (const int*)d_in[2];
  const int*   send_idx= (const int*)d_in[3];
  const float* e1_w1=(const float*)d_in[4],  *e1_b1=(const float*)d_in[5],
             * e1_w2=(const float*)d_in[6],  *e1_b2=(const float*)d_in[7],
             * e1_g =(const float*)d_in[8],  *e1_be=(const float*)d_in[9];
  const float* e2_w1=(const float*)d_in[10], *e2_b1=(const float*)d_in[11],
             * e2_w2=(const float*)d_in[12], *e2_b2=(const float*)d_in[13],
             * e2_g =(const float*)d_in[14], *e2_be=(const float*)d_in[15];
  const float* e3_w1=(const float*)d_in[16], *e3_b1=(const float*)d_in[17],
             * e3_w2=(const float*)d_in[18], *e3_b2=(const float*)d_in[19],
             * e3_g =(const float*)d_in[20], *e3_be=(const float*)d_in[21];
  const float* e4_w1=(const float*)d_in[22], *e4_b1=(const float*)d_in[23],
             * e4_w2=(const float*)d_in[24], *e4_b2=(const float*)d_in[25],
             * e4_g =(const float*)d_in[26], *e4_be=(const float*)d_in[27];
  const float* fc_w=(const float*)d_in[28], *fc_b=(const float*)d_in[29];
  const float* mw1=(const float*)d_in[30], *mb1=(const float*)d_in[31];
  const float* mw2=(const float*)d_in[32], *mb2=(const float*)d_in[33];
  const float* ow1=(const float*)d_in[34], *ob1=(const float*)d_in[35];
  const float* ow2=(const float*)d_in[36], *ob2=(const float*)d_in[37];
  const float* ow3=(const float*)d_in[38], *ob3=(const float*)d_in[39];

  char* ws = (char*)d_ws;
  size_t off = 0;
  auto alloc = [&](size_t bytes)->void*{ void* p = ws + off; off = (off + bytes + 255) & ~(size_t)255; return p; };
  bf16* W2AT = (bf16*)alloc((size_t)131072*2);
  bf16* W2BT = (bf16*)alloc((size_t)65536*2);
  bf16* W4AT = (bf16*)alloc((size_t)196608*2);
  bf16* W4BT = (bf16*)alloc((size_t)65536*2);
  bf16* MW2T = (bf16*)alloc((size_t)262144*2);
  bf16* OW1T = (bf16*)alloc((size_t)73728*2);
  bf16* OW2T = (bf16*)alloc((size_t)65536*2);
  bf16* X1   = (bf16*)alloc((size_t)65536*2);
  float* HS  = (float*)alloc((size_t)65536*4);
  bf16* ABUF = (bf16*)alloc((size_t)7936*768*2);   // A2 / A4 / Aaug
  bf16* YBF  = (bf16*)alloc((size_t)12544*256*2);  // Y2a / Y4a / P1
  float* YF32= (float*)alloc((size_t)7936*256*4);  // Y2b / Y4b
  bf16* X2   = (bf16*)alloc((size_t)7936*256*2);
  bf16* X3   = (bf16*)alloc((size_t)65536*2);
  bf16* X4   = (bf16*)alloc((size_t)7936*256*2);
  bf16* P2   = (bf16*)alloc((size_t)12544*256*2);
  float* INC = (float*)alloc((size_t)65536*4);
  float* RT  = (float*)alloc((size_t)7936*4*4);
  float* PART= (float*)alloc((size_t)124*512*4);
  float* PRM = (float*)alloc((size_t)512*4);

  float* out = (float*)d_out;
  float* prob_out = out + 49152;

  prep_weights<<<3360,256,0,stream>>>(e2_w1,e2_w2,e4_w1,e4_w2,mw2,ow1,ow2,
                                      W2AT,W2BT,W4AT,W4BT,MW2T,OW1T,OW2T);
  small_mlp<196><<<256,256,0,stream>>>(data, e1_w1,e1_b1,e1_w2,e1_b2, HS);
  bn_small<<<1,256,0,stream>>>(HS, e1_g, e1_be, X1);
  gather2<<<1984,256,0,stream>>>(X1, send_idx, recv_idx, ABUF);
  gemm_mfma<512,2,true><<<62,256,0,stream>>>(ABUF, W2AT, e2_b1, YBF);
  gemm_mfma<256,2,false><<<62,256,0,stream>>>(YBF, W2BT, e2_b2, YF32);
  bn_stats<<<124,256,0,stream>>>(YF32, PART);
  bn_finalize<<<1,256,0,stream>>>(PART, 124, e2_g, e2_be, PRM, 7936.f);
  bn_apply<<<7936,256,0,stream>>>(YF32, PRM, X2);
  seg_incoming<<<256,256,0,stream>>>(X2, INC);
  small_mlp<256><<<256,256,0,stream>>>(INC, e3_w1,e3_b1,e3_w2,e3_b2, HS);
  bn_small<<<1,256,0,stream>>>(HS, e3_g, e3_be, X3);
  gather3<<<2976,256,0,stream>>>(X3, X2, send_idx, recv_idx, ABUF);
  gemm_mfma<768,2,true><<<62,256,0,stream>>>(ABUF, W4AT, e4_b1, YBF);
  gemm_mfma<256,2,false><<<62,256,0,stream>>>(YBF, W4BT, e4_b2, YF32);
  bn_stats<<<124,256,0,stream>>>(YF32, PART);
  bn_finalize<<<1,256,0,stream>>>(PART, 124, e4_g, e4_be, PRM, 7936.f);
  bn_apply<<<7936,256,0,stream>>>(YF32, PRM, X4);
  fc_softmax<<<31,256,0,stream>>>(X4, fc_w, fc_b, gumbel, prob_out, RT);
  decoder_msg<<<3136,256,0,stream>>>(data, send_idx, RT, mw1, mb1, MW2T, mb2, ABUF);
  gemm_mfma<288,1,true><<<98,256,0,stream>>>(ABUF, OW1T, ob1, YBF);
  gemm_mfma<256,1,true><<<98,256,0,stream>>>(YBF, OW2T, ob2, P2);
  final_out<<<49,256,0,stream>>>(P2, ow3, ob3, data, out);
}